// Round 1
// baseline (114.033 us; speedup 1.0000x reference)
//
#include <hip/hip_runtime.h>
#include <math.h>

#define B_      16
#define C_IN_   128
#define C_OUT_  3
#define W_DIM_  512
#define HW_     65536          // 256*256
#define CONV_CLAMP_ 256.0f

// ---------------------------------------------------------------------------
// Kernel 1: s[b][j] = (w[b] . affine_w[j]) / sqrt(512) + affine_b[j]
// One 16-lane group per (b,j). 16*384 = 6144 groups -> 384 blocks * 256 thr.
// ---------------------------------------------------------------------------
__global__ __launch_bounds__(256) void k_styles(
        const float* __restrict__ w,
        const float* __restrict__ affine_w,
        const float* __restrict__ affine_b,
        float* __restrict__ s_out) {
    int gid   = blockIdx.x * blockDim.x + threadIdx.x;
    int group = gid >> 4;            // (b,j) pair
    int lane  = gid & 15;
    if (group >= B_ * 3 * C_IN_) return;
    int b = group / (3 * C_IN_);
    int j = group - b * (3 * C_IN_);
    const float* wrow = w        + (size_t)b * W_DIM_;
    const float* arow = affine_w + (size_t)j * W_DIM_;
    float p = 0.f;
    #pragma unroll
    for (int t = 0; t < W_DIM_ / 16; ++t) {
        int k = lane + t * 16;
        p = fmaf(wrow[k], arow[k], p);
    }
    // reduce within the 16-lane group
    #pragma unroll
    for (int off = 8; off >= 1; off >>= 1)
        p += __shfl_xor(p, off, 16);
    if (lane == 0) {
        const float fc_gain = 0.04419417382415922f;   // 1/sqrt(512)
        s_out[group] = fmaf(p, fc_gain, affine_b[j]);
    }
}

// ---------------------------------------------------------------------------
// Kernel 2: eff[b][i] = float4( style * weight[o][i] for o=0..2, 0 )
//           style = (m1*m2 + m3) / sqrt(128)
// ---------------------------------------------------------------------------
__global__ __launch_bounds__(256) void k_eff(
        const float* __restrict__ s,
        const float* __restrict__ weight,
        float* __restrict__ eff) {
    int gid = blockIdx.x * blockDim.x + threadIdx.x;   // (b,i)
    if (gid >= B_ * C_IN_) return;
    int b = gid / C_IN_;
    int i = gid - b * C_IN_;
    const float* sb = s + (size_t)b * 3 * C_IN_;
    float m1 = sb[i], m2 = sb[i + C_IN_], m3 = sb[i + 2 * C_IN_];
    float style = fmaf(m1, m2, m3) * 0.08838834764831845f;  // 1/sqrt(128)
    float4 e;
    e.x = style * weight[0 * C_IN_ + i];
    e.y = style * weight[1 * C_IN_ + i];
    e.z = style * weight[2 * C_IN_ + i];
    e.w = 0.f;
    reinterpret_cast<float4*>(eff)[gid] = e;
}

// ---------------------------------------------------------------------------
// Kernel 3 (the 512 MB pass):
// out[b][o][pix] = clip( sum_i x[b][i][pix] * eff[b][i].o + bias[o] )
// 64 blocks per batch; each thread owns 4 consecutive pixels (float4).
// ---------------------------------------------------------------------------
__global__ __launch_bounds__(256) void k_main(
        const float* __restrict__ x,
        const float* __restrict__ eff,
        const float* __restrict__ bias,
        float* __restrict__ out) {
    __shared__ float4 eff_lds[C_IN_];
    int b   = blockIdx.x >> 6;       // 64 blocks per batch
    int blk = blockIdx.x & 63;

    if (threadIdx.x < C_IN_)
        eff_lds[threadIdx.x] =
            reinterpret_cast<const float4*>(eff)[b * C_IN_ + threadIdx.x];
    __syncthreads();

    int pix = blk * 1024 + threadIdx.x * 4;     // 256 thr * 4 px = 1024 px
    const float* xb = x + (size_t)b * C_IN_ * HW_ + pix;

    float4 a0 = {0.f,0.f,0.f,0.f};
    float4 a1 = {0.f,0.f,0.f,0.f};
    float4 a2 = {0.f,0.f,0.f,0.f};

    #pragma unroll 8
    for (int i = 0; i < C_IN_; ++i) {
        float4 xv = *reinterpret_cast<const float4*>(xb + (size_t)i * HW_);
        float4 e  = eff_lds[i];
        a0.x = fmaf(xv.x, e.x, a0.x);
        a0.y = fmaf(xv.y, e.x, a0.y);
        a0.z = fmaf(xv.z, e.x, a0.z);
        a0.w = fmaf(xv.w, e.x, a0.w);
        a1.x = fmaf(xv.x, e.y, a1.x);
        a1.y = fmaf(xv.y, e.y, a1.y);
        a1.z = fmaf(xv.z, e.y, a1.z);
        a1.w = fmaf(xv.w, e.y, a1.w);
        a2.x = fmaf(xv.x, e.z, a2.x);
        a2.y = fmaf(xv.y, e.z, a2.y);
        a2.z = fmaf(xv.z, e.z, a2.z);
        a2.w = fmaf(xv.w, e.z, a2.w);
    }

    float b0 = bias[0], b1 = bias[1], b2 = bias[2];
    auto clip4 = [](float4 v, float bb) {
        float4 r;
        r.x = fminf(fmaxf(v.x + bb, -CONV_CLAMP_), CONV_CLAMP_);
        r.y = fminf(fmaxf(v.y + bb, -CONV_CLAMP_), CONV_CLAMP_);
        r.z = fminf(fmaxf(v.z + bb, -CONV_CLAMP_), CONV_CLAMP_);
        r.w = fminf(fmaxf(v.w + bb, -CONV_CLAMP_), CONV_CLAMP_);
        return r;
    };

    float* ob = out + (size_t)b * C_OUT_ * HW_ + pix;
    *reinterpret_cast<float4*>(ob)            = clip4(a0, b0);
    *reinterpret_cast<float4*>(ob + HW_)      = clip4(a1, b1);
    *reinterpret_cast<float4*>(ob + 2 * HW_)  = clip4(a2, b2);
}

// ---------------------------------------------------------------------------
extern "C" void kernel_launch(void* const* d_in, const int* in_sizes, int n_in,
                              void* d_out, int out_size, void* d_ws, size_t ws_size,
                              hipStream_t stream) {
    const float* x        = (const float*)d_in[0];
    const float* w        = (const float*)d_in[1];
    const float* weight   = (const float*)d_in[2];
    const float* bias     = (const float*)d_in[3];
    const float* affine_w = (const float*)d_in[4];
    const float* affine_b = (const float*)d_in[5];
    float* out = (float*)d_out;

    float* s_ws  = (float*)d_ws;                    // 16*384 floats
    float* eff   = s_ws + B_ * 3 * C_IN_;           // 16*128*4 floats

    k_styles<<<384, 256, 0, stream>>>(w, affine_w, affine_b, s_ws);
    k_eff   <<<8,   256, 0, stream>>>(s_ws, weight, eff);
    k_main  <<<1024,256, 0, stream>>>(x, eff, bias, out);
}